// Round 4
// baseline (189.659 us; speedup 1.0000x reference)
//
#include <hip/hip_runtime.h>

#define BATCH   4096
#define IN_F    1024
#define OUT_F   1024
#define KF      8
#define KD      (2*IN_F*KF)   /* 16384 GEMM K-dim */
#define HALF_KD (IN_F*KF)     /* 8192 */

#define BM 256
#define BN 256
#define BK 64
#define KSPLIT 4
#define KCHUNK (KD/KSPLIT)    /* 4096 */
#define NT (KCHUNK/BK)        /* 64 K-tiles per block */
#define C_ELEMS ((size_t)BATCH * OUT_F)

typedef short short8 __attribute__((ext_vector_type(8)));
typedef float f32x4  __attribute__((ext_vector_type(4)));

// bf16 round-to-nearest-even from f32 (bit pattern in ushort)
__device__ __forceinline__ unsigned short f2bf(float f) {
  union { float f; unsigned int u; } v; v.f = f;
  unsigned int u = v.u;
  unsigned int lsb = (u >> 16) & 1u;
  u += 0x7fffu + lsb;
  return (unsigned short)(u >> 16);
}

__device__ __forceinline__ void gload_lds16(const void* g, void* l) {
  __builtin_amdgcn_global_load_lds((const __attribute__((address_space(1))) void*)g,
                                   (__attribute__((address_space(3))) void*)l,
                                   16, 0, 0);
}

// ---------------- W conversion: [a | b] f32 -> bf16 [OUT_F][KD] ----------------
__global__ __launch_bounds__(256) void wconv_kernel(const float* __restrict__ a,
                                                    const float* __restrict__ b,
                                                    unsigned short* __restrict__ W) {
  size_t t = (size_t)blockIdx.x * 256 + threadIdx.x;
  size_t g = t * 8;
  int o = (int)(g >> 14);
  int f = (int)(g & (KD - 1));
  const float* src = (f < HALF_KD) ? (a + (size_t)o * HALF_KD + f)
                                   : (b + (size_t)o * HALF_KD + (f - HALF_KD));
  float4 v0 = reinterpret_cast<const float4*>(src)[0];
  float4 v1 = reinterpret_cast<const float4*>(src)[1];
  union { unsigned short h[8]; int4 v; } u;
  u.h[0] = f2bf(v0.x); u.h[1] = f2bf(v0.y); u.h[2] = f2bf(v0.z); u.h[3] = f2bf(v0.w);
  u.h[4] = f2bf(v1.x); u.h[5] = f2bf(v1.y); u.h[6] = f2bf(v1.z); u.h[7] = f2bf(v1.w);
  *reinterpret_cast<int4*>(W + g) = u.v;
}

// ---------------- feature kernel: Xf[b, i*8+k] = sin(k x), +8192 -> cos ----------------
__global__ __launch_bounds__(256) void feat_kernel(const float* __restrict__ x,
                                                   unsigned short* __restrict__ Xf) {
  int idx = blockIdx.x * 256 + threadIdx.x;
  int bb = idx >> 10;
  int i  = idx & 1023;
  float xv = x[idx];
  float s1, c1;
  sincosf(xv, &s1, &c1);
  float sv[KF], cv[KF];
  sv[0] = 0.f; cv[0] = 1.f;
  sv[1] = s1;  cv[1] = c1;
#pragma unroll
  for (int k = 2; k < KF; ++k) {
    sv[k] = sv[k-1]*c1 + cv[k-1]*s1;
    cv[k] = cv[k-1]*c1 - sv[k-1]*s1;
  }
  union { unsigned short h[8]; int4 v; } us, uc;
#pragma unroll
  for (int k = 0; k < KF; ++k) { us.h[k] = f2bf(sv[k]); uc.h[k] = f2bf(cv[k]); }
  size_t base = (size_t)bb * KD + (size_t)i * KF;
  *reinterpret_cast<int4*>(Xf + base)           = us.v;
  *reinterpret_cast<int4*>(Xf + base + HALF_KD) = uc.v;
}

// ---------------- GEMM: 256x256 tile, 8 waves, 1-barrier-per-tile pipeline ----------------
// Per-wave 128x64 output = acc[8][4]. Straight-line K-tile body: stage(t+1) issued at
// tile start (full-tile lead >> HBM latency), 24 b128 ds_reads + 64 MFMA with pure data
// deps (compiler emits fine lgkmcnt; waves drift -> one wave's MFMA hides another's
// LDS-port time). Single vmcnt(0)+s_barrier at tile end is the only sync (WAR on buf[cn]
// is guaranteed: every read feeds an MFMA that precedes the previous barrier arrival).
// T2 XOR swizzle via pre-swizzled global source + swizzled ds_read (0 conflicts, R2).
__global__ __launch_bounds__(512, 2) void gemm_kernel(const unsigned short* __restrict__ A,
                                                      const unsigned short* __restrict__ Bt,
                                                      float* __restrict__ Cout,
                                                      int use_slab) {
  __shared__ unsigned short sA[2][BM * BK];   // 32 KiB each
  __shared__ unsigned short sB[2][BN * BK];

  const int tid  = threadIdx.x;
  const int wid  = tid >> 6;
  const int lane = tid & 63;
  const int wm = wid >> 2, wn = wid & 3;

  // bijective XCD swizzle: 256 blocks % 8 XCDs == 0; 32 consecutive work items/XCD
  const int bid = blockIdx.x;
  const int s   = (bid & 7) * 32 + (bid >> 3);
  const int z   = s >> 6;          // K-split chunk 0..3 (2 XCDs per chunk)
  const int mt  = s & 15;          // m-tile fastest -> XCD shares W panels in L2
  const int nt  = (s >> 4) & 3;
  const int m0  = mt * BM;
  const int n0  = nt * BN;
  const int fbase = z * KCHUNK;

  // ---- staging addressing (pre-swizzled global source, linear LDS dest) ----
  const int srow = wid * 8 + (lane >> 3);        // row within a 64-row group
  const int gsw  = (lane & 7) ^ (lane >> 3);     // swizzled 16B granule (involution)
  const unsigned short* pA = A  + (size_t)(m0 + srow) * KD + fbase + gsw * 8;
  const unsigned short* pB = Bt + (size_t)(n0 + srow) * KD + fbase + gsw * 8;
  const int ldst = wid * 512;                    // wave-uniform LDS elem offset in group

  // ---- fragment read addressing (swizzled) ----
  const int l15 = lane & 15;
  int kfrag[2];
#pragma unroll
  for (int ks = 0; ks < 2; ++ks)
    kfrag[ks] = ((ks * 64 + (lane >> 4) * 16) ^ ((lane & 7) << 4)) >> 1;
  const int arow = wm * 128 + l15;
  const int brow = wn * 64 + l15;

  f32x4 acc[8][4] = {};

  // ---- prologue: stage tile 0 into buf 0 ----
#pragma unroll
  for (int g = 0; g < 4; ++g)
    gload_lds16(pB + (size_t)g * 64 * KD, &sB[0][g * 4096 + ldst]);
#pragma unroll
  for (int g = 0; g < 4; ++g)
    gload_lds16(pA + (size_t)g * 64 * KD, &sA[0][g * 4096 + ldst]);
  asm volatile("s_waitcnt vmcnt(0)\n\ts_barrier" ::: "memory");

  for (int t = 0; t < NT; ++t) {
    const int c  = t & 1;
    const int cn = c ^ 1;
    const int ktn = (t + 1 < NT) ? (t + 1) * BK : 0;   // wrapped dead loads on last tile keep ledger exact
    const unsigned short* sAc = &sA[c][0];
    const unsigned short* sBc = &sB[c][0];

    // stage next K-tile into the other buffer (no barrier needed before: WAR satisfied)
#pragma unroll
    for (int g = 0; g < 4; ++g)
      gload_lds16(pB + (size_t)g * 64 * KD + ktn, &sB[cn][g * 4096 + ldst]);
#pragma unroll
    for (int g = 0; g < 4; ++g)
      gload_lds16(pA + (size_t)g * 64 * KD + ktn, &sA[cn][g * 4096 + ldst]);

    // compute tile t: straight-line, compiler-scheduled lgkmcnt, waves unsynced
#pragma unroll
    for (int ks = 0; ks < 2; ++ks) {
      short8 bfr[4], afr[8];
#pragma unroll
      for (int nf = 0; nf < 4; ++nf)
        bfr[nf] = *reinterpret_cast<const short8*>(sBc + (brow + nf * 16) * 64 + kfrag[ks]);
#pragma unroll
      for (int mf = 0; mf < 8; ++mf)
        afr[mf] = *reinterpret_cast<const short8*>(sAc + (arow + mf * 16) * 64 + kfrag[ks]);
      __builtin_amdgcn_s_setprio(1);
#pragma unroll
      for (int mf = 0; mf < 8; ++mf)
#pragma unroll
        for (int nf = 0; nf < 4; ++nf)
          acc[mf][nf] = __builtin_amdgcn_mfma_f32_16x16x32_bf16(afr[mf], bfr[nf], acc[mf][nf], 0, 0, 0);
      __builtin_amdgcn_s_setprio(0);
    }

    // single sync point per tile: publish staged buf[cn] to all waves
    asm volatile("s_waitcnt vmcnt(0)\n\ts_barrier" ::: "memory");
  }

  // ---- epilogue ----
  const int crow = m0 + wm * 128 + (lane >> 4) * 4;
  const int ccol = n0 + wn * 64 + l15;
  if (use_slab) {
    float* Cz = Cout + (size_t)z * C_ELEMS;
#pragma unroll
    for (int mf = 0; mf < 8; ++mf)
#pragma unroll
      for (int nf = 0; nf < 4; ++nf)
#pragma unroll
        for (int j = 0; j < 4; ++j)
          Cz[(size_t)(crow + mf * 16 + j) * OUT_F + ccol + nf * 16] = acc[mf][nf][j];
  } else {
#pragma unroll
    for (int mf = 0; mf < 8; ++mf)
#pragma unroll
      for (int nf = 0; nf < 4; ++nf)
#pragma unroll
        for (int j = 0; j < 4; ++j)
          atomicAdd(&Cout[(size_t)(crow + mf * 16 + j) * OUT_F + ccol + nf * 16],
                    acc[mf][nf][j]);
  }
}

// ---------------- K-split slab reduce: y = s0+s1+s2+s3 (float4) ----------------
__global__ __launch_bounds__(256) void reduce_kernel(const f32x4* __restrict__ s,
                                                     f32x4* __restrict__ y) {
  size_t i = (size_t)blockIdx.x * 256 + threadIdx.x;
  const size_t NQ = C_ELEMS / 4;
  f32x4 v = s[i] + s[i + NQ] + s[i + 2 * NQ] + s[i + 3 * NQ];
  y[i] = v;
}

// ---------------- fallback (no workspace): direct f32 evaluation ----------------
__global__ __launch_bounds__(256) void naive_kernel(const float* __restrict__ x,
                                                    const float* __restrict__ a,
                                                    const float* __restrict__ b,
                                                    float* __restrict__ y) {
  int o  = blockIdx.x * 256 + threadIdx.x;
  int bb = blockIdx.y;
  __shared__ float xs[IN_F];
  for (int i = threadIdx.x; i < IN_F; i += 256) xs[i] = x[(size_t)bb * IN_F + i];
  __syncthreads();
  float acc = 0.f;
  for (int i = 0; i < IN_F; ++i) {
    float s1, c1; sincosf(xs[i], &s1, &c1);
    float sk = 0.f, ck = 1.f;
    const float* ap = a + (size_t)o * HALF_KD + i * KF;
    const float* bp = b + (size_t)o * HALF_KD + i * KF;
#pragma unroll
    for (int k = 0; k < KF; ++k) {
      acc += sk * ap[k] + ck * bp[k];
      float sn = sk * c1 + ck * s1;
      ck = ck * c1 - sk * s1;
      sk = sn;
    }
  }
  y[(size_t)bb * OUT_F + o] = acc;
}

extern "C" void kernel_launch(void* const* d_in, const int* in_sizes, int n_in,
                              void* d_out, int out_size, void* d_ws, size_t ws_size,
                              hipStream_t stream) {
  (void)in_sizes; (void)n_in; (void)out_size;
  const float* x = (const float*)d_in[0];
  const float* a = (const float*)d_in[1];
  const float* b = (const float*)d_in[2];
  float* y = (float*)d_out;

  const size_t XF_BYTES   = (size_t)BATCH * KD * sizeof(unsigned short);   // 128 MiB
  const size_t W_BYTES    = (size_t)OUT_F * KD * sizeof(unsigned short);   // 32 MiB
  const size_t SLAB_BYTES = C_ELEMS * sizeof(float) * KSPLIT;              // 64 MiB

  if (ws_size >= XF_BYTES + W_BYTES) {
    unsigned short* Xf = (unsigned short*)d_ws;
    unsigned short* W  = (unsigned short*)((char*)d_ws + XF_BYTES);
    const bool slab = ws_size >= XF_BYTES + W_BYTES + SLAB_BYTES;
    float* slabs = (float*)((char*)d_ws + XF_BYTES + W_BYTES);

    wconv_kernel<<<(OUT_F * KD / 8) / 256, 256, 0, stream>>>(a, b, W);
    feat_kernel<<<(BATCH * IN_F) / 256, 256, 0, stream>>>(x, Xf);
    if (slab) {
      gemm_kernel<<<dim3((BATCH / BM) * (OUT_F / BN) * KSPLIT), 512, 0, stream>>>(Xf, W, slabs, 1);
      reduce_kernel<<<(int)(C_ELEMS / 4 / 256), 256, 0, stream>>>((const f32x4*)slabs, (f32x4*)y);
    } else {
      hipMemsetAsync(d_out, 0, C_ELEMS * sizeof(float), stream);
      gemm_kernel<<<dim3((BATCH / BM) * (OUT_F / BN) * KSPLIT), 512, 0, stream>>>(Xf, W, y, 0);
    }
  } else {
    naive_kernel<<<dim3(OUT_F / 256, BATCH), 256, 0, stream>>>(x, a, b, y);
  }
}

// Round 5
// 176.668 us; speedup vs baseline: 1.0735x; 1.0735x over previous
//
#include <hip/hip_runtime.h>

#define BATCH   4096
#define IN_F    1024
#define OUT_F   1024
#define KF      8
#define KD      (2*IN_F*KF)   /* 16384 GEMM K-dim */
#define HALF_KD (IN_F*KF)     /* 8192 */

#define BM 256
#define BN 256
#define BK 64
#define KSPLIT 4
#define KCHUNK (KD/KSPLIT)    /* 4096 */
#define NT (KCHUNK/BK)        /* 64 K-tiles per block */
#define C_ELEMS ((size_t)BATCH * OUT_F)

typedef short short8 __attribute__((ext_vector_type(8)));
typedef float f32x4  __attribute__((ext_vector_type(4)));

// bf16 round-to-nearest-even from f32 (bit pattern in ushort)
__device__ __forceinline__ unsigned short f2bf(float f) {
  union { float f; unsigned int u; } v; v.f = f;
  unsigned int u = v.u;
  unsigned int lsb = (u >> 16) & 1u;
  u += 0x7fffu + lsb;
  return (unsigned short)(u >> 16);
}

__device__ __forceinline__ void gload_lds16(const void* g, void* l) {
  __builtin_amdgcn_global_load_lds((const __attribute__((address_space(1))) void*)g,
                                   (__attribute__((address_space(3))) void*)l,
                                   16, 0, 0);
}

// ---------------- W conversion: [a | b] f32 -> bf16 [OUT_F][KD] ----------------
__global__ __launch_bounds__(256) void wconv_kernel(const float* __restrict__ a,
                                                    const float* __restrict__ b,
                                                    unsigned short* __restrict__ W) {
  size_t t = (size_t)blockIdx.x * 256 + threadIdx.x;
  size_t g = t * 8;
  int o = (int)(g >> 14);
  int f = (int)(g & (KD - 1));
  const float* src = (f < HALF_KD) ? (a + (size_t)o * HALF_KD + f)
                                   : (b + (size_t)o * HALF_KD + (f - HALF_KD));
  float4 v0 = reinterpret_cast<const float4*>(src)[0];
  float4 v1 = reinterpret_cast<const float4*>(src)[1];
  union { unsigned short h[8]; int4 v; } u;
  u.h[0] = f2bf(v0.x); u.h[1] = f2bf(v0.y); u.h[2] = f2bf(v0.z); u.h[3] = f2bf(v0.w);
  u.h[4] = f2bf(v1.x); u.h[5] = f2bf(v1.y); u.h[6] = f2bf(v1.z); u.h[7] = f2bf(v1.w);
  *reinterpret_cast<int4*>(W + g) = u.v;
}

// ---------------- feature kernel: Xf[b, i*8+k] = sin(k x), +8192 -> cos ----------------
__global__ __launch_bounds__(256) void feat_kernel(const float* __restrict__ x,
                                                   unsigned short* __restrict__ Xf) {
  int idx = blockIdx.x * 256 + threadIdx.x;
  int bb = idx >> 10;
  int i  = idx & 1023;
  float xv = x[idx];
  float s1, c1;
  sincosf(xv, &s1, &c1);
  float sv[KF], cv[KF];
  sv[0] = 0.f; cv[0] = 1.f;
  sv[1] = s1;  cv[1] = c1;
#pragma unroll
  for (int k = 2; k < KF; ++k) {
    sv[k] = sv[k-1]*c1 + cv[k-1]*s1;
    cv[k] = cv[k-1]*c1 - sv[k-1]*s1;
  }
  union { unsigned short h[8]; int4 v; } us, uc;
#pragma unroll
  for (int k = 0; k < KF; ++k) { us.h[k] = f2bf(sv[k]); uc.h[k] = f2bf(cv[k]); }
  size_t base = (size_t)bb * KD + (size_t)i * KF;
  *reinterpret_cast<int4*>(Xf + base)           = us.v;
  *reinterpret_cast<int4*>(Xf + base + HALF_KD) = uc.v;
}

// ---------------- GEMM: 256x256 tile, 8 waves, m201-style 8-phase pipeline ----------------
// Iteration = 2 K-tiles (buf0/buf1), 8 phases x 16 MFMA. Per phase: 4 ds_read_b128 af
// (+8 bf at q0, held in regs all tile), 2 gload_lds stage, [lgkmcnt(8)@q0], BAR,
// setprio(1), 16 MFMA, setprio(0), [vmcnt(4)@q3], BAR.
// Stage ledger (per-wave outstanding): P1,P2: A(2j+1)->sA[1]; P3,P4: B(2j+2)->sB[0];
// P5,P6: A(2j+2)->sA[0]; P7,P8: B(2j+3)->sB[1]. vmcnt(4)@P4 retires tile 2j+1
// (B from prev P7P8 + A from P1P2); vmcnt(4)@P8 retires tile 2j+2. Min 2-phase lead,
// never vmcnt(0) in loop. WAR: B-buffers free after q0 (bf in regs), A after q3 --
// every overwrite is >=1 barrier after its readers' last use.
// T2 XOR swizzle via pre-swizzled global source + swizzled ds_read (0 conflicts, R2).
__global__ __launch_bounds__(512, 2) void gemm_kernel(const unsigned short* __restrict__ A,
                                                      const unsigned short* __restrict__ Bt,
                                                      float* __restrict__ Cout,
                                                      int use_slab) {
  __shared__ unsigned short sA[2][BM * BK];   // 32 KiB each
  __shared__ unsigned short sB[2][BN * BK];

  const int tid  = threadIdx.x;
  const int wid  = tid >> 6;
  const int lane = tid & 63;
  const int wm = wid >> 2, wn = wid & 3;

  // bijective XCD swizzle: 256 blocks % 8 XCDs == 0; 32 consecutive work items/XCD
  const int bid = blockIdx.x;
  const int s   = (bid & 7) * 32 + (bid >> 3);
  const int z   = s >> 6;          // K-split chunk 0..3 (2 XCDs per chunk)
  const int mt  = s & 15;          // m-tile fastest -> XCD shares W panels in L2
  const int nt  = (s >> 4) & 3;
  const int m0  = mt * BM;
  const int n0  = nt * BN;
  const int fbase = z * KCHUNK;

  // ---- staging addressing (pre-swizzled global source, linear LDS dest) ----
  const int srow = wid * 8 + (lane >> 3);        // row within a 64-row group
  const int gsw  = (lane & 7) ^ (lane >> 3);     // swizzled 16B granule (involution)
  const unsigned short* pA = A  + (size_t)(m0 + srow) * KD + fbase + gsw * 8;
  const unsigned short* pB = Bt + (size_t)(n0 + srow) * KD + fbase + gsw * 8;
  const int ldst = wid * 512;                    // wave-uniform LDS elem offset in group

  // ---- fragment read addressing (swizzled) ----
  const int l15 = lane & 15;
  int kfrag[2];
#pragma unroll
  for (int ks = 0; ks < 2; ++ks)
    kfrag[ks] = ((ks * 64 + (lane >> 4) * 16) ^ ((lane & 7) << 4)) >> 1;
  const int arow = wm * 128 + l15;
  const int brow = wn * 64 + l15;

  f32x4 acc[8][4] = {};
  short8 bfr[4][2];

  // One phase: reads + 2 stage loads + barrier + 16 MFMA + (vmcnt@q3) + barrier.
#define PHASE(SAC, SBC, Q, STGP, STGDST, G0, KOFF)                              \
  {                                                                             \
    short8 af[2][2];                                                            \
    _Pragma("unroll") for (int i = 0; i < 2; ++i)                               \
      _Pragma("unroll") for (int ks = 0; ks < 2; ++ks)                          \
        af[i][ks] = *reinterpret_cast<const short8*>(                           \
            (SAC) + (arow + (2*(Q)+i)*16)*64 + kfrag[ks]);                      \
    if ((Q) == 0) {                                                             \
      _Pragma("unroll") for (int nf = 0; nf < 4; ++nf)                          \
        _Pragma("unroll") for (int ks = 0; ks < 2; ++ks)                        \
          bfr[nf][ks] = *reinterpret_cast<const short8*>(                       \
              (SBC) + (brow + nf*16)*64 + kfrag[ks]);                           \
    }                                                                           \
    gload_lds16((STGP) + (size_t)((G0)    ) * 64 * KD + (KOFF),                 \
                (STGDST) + ((G0)    ) * 4096 + ldst);                           \
    gload_lds16((STGP) + (size_t)((G0) + 1) * 64 * KD + (KOFF),                 \
                (STGDST) + ((G0) + 1) * 4096 + ldst);                           \
    if ((Q) == 0) asm volatile("s_waitcnt lgkmcnt(8)" ::: "memory");            \
    asm volatile("s_barrier" ::: "memory");                                     \
    __builtin_amdgcn_s_setprio(1);                                              \
    _Pragma("unroll") for (int i = 0; i < 2; ++i)                               \
      _Pragma("unroll") for (int nf = 0; nf < 4; ++nf)                          \
        _Pragma("unroll") for (int ks = 0; ks < 2; ++ks)                        \
          acc[2*(Q)+i][nf] = __builtin_amdgcn_mfma_f32_16x16x32_bf16(           \
              af[i][ks], bfr[nf][ks], acc[2*(Q)+i][nf], 0, 0, 0);               \
    __builtin_amdgcn_s_setprio(0);                                              \
    if ((Q) == 3) asm volatile("s_waitcnt vmcnt(4)" ::: "memory");              \
    asm volatile("s_barrier" ::: "memory");                                     \
  }

  // ---- prologue: stage tile0 (A+B) -> buf0, B(tile1) -> sB[1]; retire tile0 ----
#pragma unroll
  for (int g = 0; g < 4; ++g) {
    gload_lds16(pB + (size_t)g * 64 * KD, &sB[0][g * 4096 + ldst]);
    gload_lds16(pA + (size_t)g * 64 * KD, &sA[0][g * 4096 + ldst]);
  }
#pragma unroll
  for (int g = 0; g < 4; ++g)
    gload_lds16(pB + (size_t)g * 64 * KD + BK, &sB[1][g * 4096 + ldst]);
  asm volatile("s_waitcnt vmcnt(4)" ::: "memory");   // tile0 resident; B(1) in flight
  asm volatile("s_barrier" ::: "memory");

  for (int j = 0; j < NT / 2; ++j) {
    const int kA1 = (2 * j + 1) * BK;                           // tile 2j+1 (always real)
    const int kB2 = (2 * j + 2 < NT) ? (2 * j + 2) * BK : 0;    // tile 2j+2 (dead-wrap at end)
    const int kB3 = (2 * j + 3 < NT) ? (2 * j + 3) * BK : 0;    // tile 2j+3

    // ---- tile 2j from buf0; stage A(2j+1)->sA[1], B(2j+2)->sB[0] ----
    PHASE(&sA[0][0], &sB[0][0], 0, pA, &sA[1][0], 0, kA1)
    PHASE(&sA[0][0], &sB[0][0], 1, pA, &sA[1][0], 2, kA1)
    PHASE(&sA[0][0], &sB[0][0], 2, pB, &sB[0][0], 0, kB2)
    PHASE(&sA[0][0], &sB[0][0], 3, pB, &sB[0][0], 2, kB2)
    // ---- tile 2j+1 from buf1; stage A(2j+2)->sA[0], B(2j+3)->sB[1] ----
    PHASE(&sA[1][0], &sB[1][0], 0, pA, &sA[0][0], 0, kB2)
    PHASE(&sA[1][0], &sB[1][0], 1, pA, &sA[0][0], 2, kB2)
    PHASE(&sA[1][0], &sB[1][0], 2, pB, &sB[1][0], 0, kB3)
    PHASE(&sA[1][0], &sB[1][0], 3, pB, &sB[1][0], 2, kB3)
  }
#undef PHASE

  // ---- epilogue ----
  const int crow = m0 + wm * 128 + (lane >> 4) * 4;
  const int ccol = n0 + wn * 64 + l15;
  if (use_slab) {
    float* Cz = Cout + (size_t)z * C_ELEMS;
#pragma unroll
    for (int mf = 0; mf < 8; ++mf)
#pragma unroll
      for (int nf = 0; nf < 4; ++nf)
#pragma unroll
        for (int j = 0; j < 4; ++j)
          Cz[(size_t)(crow + mf * 16 + j) * OUT_F + ccol + nf * 16] = acc[mf][nf][j];
  } else {
#pragma unroll
    for (int mf = 0; mf < 8; ++mf)
#pragma unroll
      for (int nf = 0; nf < 4; ++nf)
#pragma unroll
        for (int j = 0; j < 4; ++j)
          atomicAdd(&Cout[(size_t)(crow + mf * 16 + j) * OUT_F + ccol + nf * 16],
                    acc[mf][nf][j]);
  }
}

// ---------------- K-split slab reduce: y = s0+s1+s2+s3 (float4) ----------------
__global__ __launch_bounds__(256) void reduce_kernel(const f32x4* __restrict__ s,
                                                     f32x4* __restrict__ y) {
  size_t i = (size_t)blockIdx.x * 256 + threadIdx.x;
  const size_t NQ = C_ELEMS / 4;
  f32x4 v = s[i] + s[i + NQ] + s[i + 2 * NQ] + s[i + 3 * NQ];
  y[i] = v;
}

// ---------------- fallback (no workspace): direct f32 evaluation ----------------
__global__ __launch_bounds__(256) void naive_kernel(const float* __restrict__ x,
                                                    const float* __restrict__ a,
                                                    const float* __restrict__ b,
                                                    float* __restrict__ y) {
  int o  = blockIdx.x * 256 + threadIdx.x;
  int bb = blockIdx.y;
  __shared__ float xs[IN_F];
  for (int i = threadIdx.x; i < IN_F; i += 256) xs[i] = x[(size_t)bb * IN_F + i];
  __syncthreads();
  float acc = 0.f;
  for (int i = 0; i < IN_F; ++i) {
    float s1, c1; sincosf(xs[i], &s1, &c1);
    float sk = 0.f, ck = 1.f;
    const float* ap = a + (size_t)o * HALF_KD + i * KF;
    const float* bp = b + (size_t)o * HALF_KD + i * KF;
#pragma unroll
    for (int k = 0; k < KF; ++k) {
      acc += sk * ap[k] + ck * bp[k];
      float sn = sk * c1 + ck * s1;
      ck = ck * c1 - sk * s1;
      sk = sn;
    }
  }
  y[(size_t)bb * OUT_F + o] = acc;
}

extern "C" void kernel_launch(void* const* d_in, const int* in_sizes, int n_in,
                              void* d_out, int out_size, void* d_ws, size_t ws_size,
                              hipStream_t stream) {
  (void)in_sizes; (void)n_in; (void)out_size;
  const float* x = (const float*)d_in[0];
  const float* a = (const float*)d_in[1];
  const float* b = (const float*)d_in[2];
  float* y = (float*)d_out;

  const size_t XF_BYTES   = (size_t)BATCH * KD * sizeof(unsigned short);   // 128 MiB
  const size_t W_BYTES    = (size_t)OUT_F * KD * sizeof(unsigned short);   // 32 MiB
  const size_t SLAB_BYTES = C_ELEMS * sizeof(float) * KSPLIT;              // 64 MiB

  if (ws_size >= XF_BYTES + W_BYTES) {
    unsigned short* Xf = (unsigned short*)d_ws;
    unsigned short* W  = (unsigned short*)((char*)d_ws + XF_BYTES);
    const bool slab = ws_size >= XF_BYTES + W_BYTES + SLAB_BYTES;
    float* slabs = (float*)((char*)d_ws + XF_BYTES + W_BYTES);

    wconv_kernel<<<(OUT_F * KD / 8) / 256, 256, 0, stream>>>(a, b, W);
    feat_kernel<<<(BATCH * IN_F) / 256, 256, 0, stream>>>(x, Xf);
    if (slab) {
      gemm_kernel<<<dim3((BATCH / BM) * (OUT_F / BN) * KSPLIT), 512, 0, stream>>>(Xf, W, slabs, 1);
      reduce_kernel<<<(int)(C_ELEMS / 4 / 256), 256, 0, stream>>>((const f32x4*)slabs, (f32x4*)y);
    } else {
      hipMemsetAsync(d_out, 0, C_ELEMS * sizeof(float), stream);
      gemm_kernel<<<dim3((BATCH / BM) * (OUT_F / BN) * KSPLIT), 512, 0, stream>>>(Xf, W, y, 0);
    }
  } else {
    naive_kernel<<<dim3(OUT_F / 256, BATCH), 256, 0, stream>>>(x, a, b, y);
  }
}